// Round 3
// baseline (722.626 us; speedup 1.0000x reference)
//
#include <hip/hip_runtime.h>
#include <math.h>

static constexpr int M_ROWS   = 200000;
static constexpr int NUM_NODE = 150;
static constexpr int ROW_F4   = NUM_NODE;            // 150 float4 per row
static constexpr int RPG      = 16;                  // rows per group
static constexpr int GROUPS   = M_ROWS / RPG;        // 12500
static constexpr int GRID     = 2500;                // 12500/2500 = 5 groups per block, exact
static constexpr int GPB      = GROUPS / GRID;       // 5
static constexpr int F4_PER_GROUP = RPG * ROW_F4;    // 2400 float4 = 38400 B
static constexpr int THREADS  = 256;

__global__ __launch_bounds__(256) void obstacle_to_lane_kernel(
    const float* __restrict__ lf,       // (M, 150, 4) f32
    const float* __restrict__ obs_pos,  // (N, 2) f32
    const int*   __restrict__ mask,     // (M, 1) i32
    float*       __restrict__ out)      // [M*2 proj | M*2 idx | M*2 rep]
{
    __shared__ float4 sbuf[2][F4_PER_GROUP];   // 2 x 38400 B
    __shared__ int    smask[2][RPG];

    const int tid  = threadIdx.x;
    const int wave = tid >> 6;
    const int lane = tid & 63;

    // ---- copy-shaped staging: 16 rows -> LDS, ~10 independent coalesced float4 loads/thread ----
    auto stage = [&](int buf, int grp) {
        const float4* src = reinterpret_cast<const float4*>(lf) + (size_t)grp * F4_PER_GROUP;
        #pragma unroll
        for (int k = 0; k < 10; ++k) {
            const int idx = tid + k * THREADS;       // 2400 = 9*256 + 96
            if (idx < F4_PER_GROUP) sbuf[buf][idx] = src[idx];
        }
        if (tid < RPG) smask[buf][tid] = mask[grp * RPG + tid];
    };

    auto compute = [&](int buf, int grp) {
        #pragma unroll 1
        for (int rr = 0; rr < RPG / 4; ++rr) {       // 4 rows per wave
            const int r = wave * (RPG / 4) + rr;     // local row 0..15
            const int m = grp * RPG + r;

            const int o  = smask[buf][r];
            const float rx = obs_pos[2 * o];
            const float ry = obs_pos[2 * o + 1];

            const float4* row = &sbuf[buf][r * ROW_F4];
            const float4 c0 = row[lane];
            const float4 c1 = row[lane + 64];
            const float4 c2 = row[(lane + 128 < NUM_NODE) ? (lane + 128) : (NUM_NODE - 1)];

            // ---- argmin over nodes 1..148 of (x-rx)^2 + (y-ry)^2 ----
            float best_d = INFINITY;
            int   best_j = 1 << 30;
            {
                float dx, dy, d;
                dx = __fsub_rn(c0.x, rx); dy = __fsub_rn(c0.y, ry);
                d  = __fadd_rn(__fmul_rn(dx, dx), __fmul_rn(dy, dy));
                if (lane >= 1 && d < best_d) { best_d = d; best_j = lane; }
                dx = __fsub_rn(c1.x, rx); dy = __fsub_rn(c1.y, ry);
                d  = __fadd_rn(__fmul_rn(dx, dx), __fmul_rn(dy, dy));
                if (d < best_d) { best_d = d; best_j = lane + 64; }
                dx = __fsub_rn(c2.x, rx); dy = __fsub_rn(c2.y, ry);
                d  = __fadd_rn(__fmul_rn(dx, dx), __fmul_rn(dy, dy));
                if (lane + 128 <= NUM_NODE - 2 && d < best_d) { best_d = d; best_j = lane + 128; }
            }
            // wave-wide argmin; ties -> smaller index (jnp.argmin semantics)
            #pragma unroll
            for (int off = 32; off > 0; off >>= 1) {
                const float od = __shfl_down(best_d, off, 64);
                const int   oj = __shfl_down(best_j, off, 64);
                if (od < best_d || (od == best_d && oj < best_j)) { best_d = od; best_j = oj; }
            }
            const int min_idx = __shfl(best_j, 0, 64);

            // ---- neighbors via register shuffles; node q on lane (q&63), group (q>>6) ----
            auto pick = [&](int q) -> float4 {
                const int sl = q & 63;
                const int g  = q >> 6;                   // wave-uniform
                const float4 s = (g == 0) ? c0 : ((g == 1) ? c1 : c2);
                float4 res;
                res.x = __shfl(s.x, sl, 64);
                res.y = __shfl(s.y, sl, 64);
                res.z = __shfl(s.z, sl, 64);
                res.w = __shfl(s.w, sl, 64);
                return res;
            };
            const float4 na = pick(min_idx - 1);
            const float4 nc = pick(min_idx);
            const float4 nb = pick(min_idx + 1);

            // dist_prev / dist_next, numpy left-to-right order, no FMA contraction
            float t, s;
            t = __fsub_rn(na.x, nc.x); s = __fmul_rn(t, t);
            t = __fsub_rn(na.y, nc.y); s = __fadd_rn(s, __fmul_rn(t, t));
            t = __fsub_rn(na.z, nc.z); s = __fadd_rn(s, __fmul_rn(t, t));
            t = __fsub_rn(na.w, nc.w); s = __fadd_rn(s, __fmul_rn(t, t));
            const float dist_prev = s;
            t = __fsub_rn(nb.x, nc.x); s = __fmul_rn(t, t);
            t = __fsub_rn(nb.y, nc.y); s = __fadd_rn(s, __fmul_rn(t, t));
            t = __fsub_rn(nb.z, nc.z); s = __fadd_rn(s, __fmul_rn(t, t));
            t = __fsub_rn(nb.w, nc.w); s = __fadd_rn(s, __fmul_rn(t, t));
            const float dist_next = s;

            float sx, sy, ex, ey;
            int ib;
            if (dist_next < dist_prev) {            // before=min_idx, after=min_idx+1
                ib = min_idx;     sx = nc.x; sy = nc.y; ex = nb.x; ey = nb.y;
            } else {                                // before=min_idx-1, after=min_idx
                ib = min_idx - 1; sx = na.x; sy = na.y; ex = nc.x; ey = nc.y;
            }

            const float lvx = __fsub_rn(ex, sx);
            const float lvy = __fsub_rn(ey, sy);
            const float mag = __fsqrt_rn(__fadd_rn(__fmul_rn(lvx, lvx), __fmul_rn(lvy, lvy)));
            const float ux  = __fdiv_rn(lvx, mag);
            const float uy  = __fdiv_rn(lvy, mag);
            const float pm  = __fadd_rn(__fmul_rn(__fsub_rn(rx, sx), ux),
                                        __fmul_rn(__fsub_rn(ry, sy), uy));
            const float px  = __fadd_rn(sx, __fmul_rn(pm, ux));
            const float py  = __fadd_rn(sy, __fmul_rn(pm, uy));

            if (lane < 3) {
                float2 v; size_t off;
                if (lane == 0)      { v = make_float2(px, py);                        off = 2 * (size_t)m; }
                else if (lane == 1) { v = make_float2((float)ib, (float)(ib + 1));    off = 2 * (size_t)M_ROWS + 2 * (size_t)m; }
                else                { v = make_float2(rx, ry);                        off = 4 * (size_t)M_ROWS + 2 * (size_t)m; }
                *reinterpret_cast<float2*>(out + off) = v;
            }
        }
    };

    // ---- double-buffered pipeline over this block's 5 groups ----
    const int g0 = blockIdx.x;
    stage(0, g0);
    int cur = 0;
    #pragma unroll 1
    for (int i = 0; i < GPB; ++i) {
        __syncthreads();                              // stage(buf[cur]) done; prev compute on buf[cur^1] done
        if (i + 1 < GPB) stage(cur ^ 1, g0 + (i + 1) * GRID);
        compute(cur, g0 + i * GRID);
        cur ^= 1;
    }
}

extern "C" void kernel_launch(void* const* d_in, const int* in_sizes, int n_in,
                              void* d_out, int out_size, void* d_ws, size_t ws_size,
                              hipStream_t stream) {
    const float* lf      = (const float*)d_in[0];
    const float* obs_pos = (const float*)d_in[1];
    const int*   mask    = (const int*)d_in[2];
    float*       out     = (float*)d_out;

    hipLaunchKernelGGL(obstacle_to_lane_kernel, dim3(GRID), dim3(THREADS), 0, stream,
                       lf, obs_pos, mask, out);
}

// Round 4
// 626.714 us; speedup vs baseline: 1.1530x; 1.1530x over previous
//
#include <hip/hip_runtime.h>
#include <math.h>

static constexpr int M_ROWS   = 200000;
static constexpr int NUM_NODE = 150;
static constexpr int ROW_F    = NUM_NODE * 4;     // 600 floats per row
static constexpr int RPW      = 6;                // rows per wave
static constexpr int RPB      = 4 * RPW;          // 24 rows per block (4 waves)
static constexpr int GRID     = (M_ROWS + RPB - 1) / RPB;   // 8334

__global__ __launch_bounds__(256) void obstacle_to_lane_kernel(
    const float* __restrict__ lf,       // (M, 150, 4) f32
    const float* __restrict__ obs_pos,  // (N, 2) f32
    const int*   __restrict__ mask,     // (M, 1) i32
    float*       __restrict__ out)      // [M*2 proj | M*2 idx | M*2 rep]
{
    const int wave = threadIdx.x >> 6;
    const int lane = threadIdx.x & 63;
    const int m0   = blockIdx.x * RPB + wave * RPW;

    int nrows = M_ROWS - m0;
    if (nrows <= 0) return;
    if (nrows > RPW) nrows = RPW;

    const int  j0   = lane;                                   // 0..63
    const int  j1   = lane + 64;                              // 64..127 (all <= 148)
    const int  j2   = lane + 128;
    const int  j2c  = (j2 < NUM_NODE) ? j2 : (NUM_NODE - 1);  // clamp for load safety
    const bool a0ok = (lane >= 1);                            // argmin domain [1,148]
    const bool a2ok = (j2 <= NUM_NODE - 2);                   // lanes 0..20

    // ---------- phase 1: issue ALL loads for 6 rows up front (xy only, stride-16) ----------
    // 18 independent float2 loads (full cache lines still stream from HBM -> 14.4 KB
    // of lines in flight per wave) + 6 independent mask->obs_pos chains.
    float2 q0[RPW], q1[RPW], q2[RPW];
    float  rx[RPW], ry[RPW];
    #pragma unroll
    for (int r = 0; r < RPW; ++r) {
        if (r < nrows) {
            const float* row = lf + (size_t)(m0 + r) * ROW_F;
            q0[r] = *reinterpret_cast<const float2*>(row + 4 * j0);
            q1[r] = *reinterpret_cast<const float2*>(row + 4 * j1);
            q2[r] = *reinterpret_cast<const float2*>(row + 4 * j2c);
            const int o = mask[m0 + r];
            rx[r] = obs_pos[2 * o];
            ry[r] = obs_pos[2 * o + 1];
        }
    }

    // ---------- phase 2: per-lane argmin over nodes 1..148, 6 rows interleaved ----------
    float bd[RPW];
    int   bj[RPW];
    #pragma unroll
    for (int r = 0; r < RPW; ++r) {
        bd[r] = INFINITY;
        bj[r] = 1 << 30;
        if (r < nrows) {
            float dx, dy, d;
            dx = __fsub_rn(q0[r].x, rx[r]); dy = __fsub_rn(q0[r].y, ry[r]);
            d  = __fadd_rn(__fmul_rn(dx, dx), __fmul_rn(dy, dy));
            if (a0ok && d < bd[r]) { bd[r] = d; bj[r] = j0; }
            dx = __fsub_rn(q1[r].x, rx[r]); dy = __fsub_rn(q1[r].y, ry[r]);
            d  = __fadd_rn(__fmul_rn(dx, dx), __fmul_rn(dy, dy));
            if (d < bd[r]) { bd[r] = d; bj[r] = j1; }
            dx = __fsub_rn(q2[r].x, rx[r]); dy = __fsub_rn(q2[r].y, ry[r]);
            d  = __fadd_rn(__fmul_rn(dx, dx), __fmul_rn(dy, dy));
            if (a2ok && d < bd[r]) { bd[r] = d; bj[r] = j2; }
        }
    }

    // ---------- wave-wide argmin reductions, 6 rows' shuffle chains interleaved ----------
    // ties -> smaller index (jnp.argmin semantics)
    #pragma unroll
    for (int off = 32; off > 0; off >>= 1) {
        #pragma unroll
        for (int r = 0; r < RPW; ++r) {
            const float od = __shfl_down(bd[r], off, 64);
            const int   oj = __shfl_down(bj[r], off, 64);
            if (od < bd[r] || (od == bd[r] && oj < bj[r])) { bd[r] = od; bj[r] = oj; }
        }
    }

    // ---------- phase 3: per-row epilogue; neighbor nodes via uniform float4 re-reads ----------
    // the 6 rows (14.4 KB) are L1-resident from phase 1 -> cheap full-node gathers
    #pragma unroll
    for (int r = 0; r < RPW; ++r) {
        if (r < nrows) {
            const int m       = m0 + r;
            const int min_idx = __shfl(bj[r], 0, 64);
            const float* row  = lf + (size_t)m * ROW_F;

            const float4 a = *reinterpret_cast<const float4*>(row + 4 * (min_idx - 1));
            const float4 c = *reinterpret_cast<const float4*>(row + 4 * min_idx);
            const float4 b = *reinterpret_cast<const float4*>(row + 4 * (min_idx + 1));

            // dist_prev / dist_next over all 4 features, numpy left-to-right order, no FMA
            float t, s;
            t = __fsub_rn(a.x, c.x); s = __fmul_rn(t, t);
            t = __fsub_rn(a.y, c.y); s = __fadd_rn(s, __fmul_rn(t, t));
            t = __fsub_rn(a.z, c.z); s = __fadd_rn(s, __fmul_rn(t, t));
            t = __fsub_rn(a.w, c.w); s = __fadd_rn(s, __fmul_rn(t, t));
            const float dist_prev = s;
            t = __fsub_rn(b.x, c.x); s = __fmul_rn(t, t);
            t = __fsub_rn(b.y, c.y); s = __fadd_rn(s, __fmul_rn(t, t));
            t = __fsub_rn(b.z, c.z); s = __fadd_rn(s, __fmul_rn(t, t));
            t = __fsub_rn(b.w, c.w); s = __fadd_rn(s, __fmul_rn(t, t));
            const float dist_next = s;

            float sx, sy, ex, ey;
            int ib;
            if (dist_next < dist_prev) {            // before=min_idx, after=min_idx+1
                ib = min_idx;     sx = c.x; sy = c.y; ex = b.x; ey = b.y;
            } else {                                // before=min_idx-1, after=min_idx
                ib = min_idx - 1; sx = a.x; sy = a.y; ex = c.x; ey = c.y;
            }

            const float lvx = __fsub_rn(ex, sx);
            const float lvy = __fsub_rn(ey, sy);
            const float mag = __fsqrt_rn(__fadd_rn(__fmul_rn(lvx, lvx), __fmul_rn(lvy, lvy)));
            const float ux  = __fdiv_rn(lvx, mag);
            const float uy  = __fdiv_rn(lvy, mag);
            const float pm  = __fadd_rn(__fmul_rn(__fsub_rn(rx[r], sx), ux),
                                        __fmul_rn(__fsub_rn(ry[r], sy), uy));
            const float px  = __fadd_rn(sx, __fmul_rn(pm, ux));
            const float py  = __fadd_rn(sy, __fmul_rn(pm, uy));

            if (lane < 3) {
                float2 v; size_t off;
                if (lane == 0)      { v = make_float2(px, py);                     off = 2 * (size_t)m; }
                else if (lane == 1) { v = make_float2((float)ib, (float)(ib + 1)); off = 2 * (size_t)M_ROWS + 2 * (size_t)m; }
                else                { v = make_float2(rx[r], ry[r]);               off = 4 * (size_t)M_ROWS + 2 * (size_t)m; }
                *reinterpret_cast<float2*>(out + off) = v;
            }
        }
    }
}

extern "C" void kernel_launch(void* const* d_in, const int* in_sizes, int n_in,
                              void* d_out, int out_size, void* d_ws, size_t ws_size,
                              hipStream_t stream) {
    const float* lf      = (const float*)d_in[0];
    const float* obs_pos = (const float*)d_in[1];
    const int*   mask    = (const int*)d_in[2];
    float*       out     = (float*)d_out;

    hipLaunchKernelGGL(obstacle_to_lane_kernel, dim3(GRID), dim3(256), 0, stream,
                       lf, obs_pos, mask, out);
}